// Round 9
// baseline (668.484 us; speedup 1.0000x reference)
//
#include <hip/hip_runtime.h>
#include <hip/hip_bf16.h>
#include <stdint.h>

// ---------------- problem constants ----------------
#define E_ 8
#define C_ 1024
#define H_ 2752
#define NTOK 8192            // B*T = 4*2048
#define CAP_ROWS 17408       // 16384 assignments + 8*128 pad, 128-aligned
#define ROUTED_XB 136        // CAP_ROWS/128
#define SHARED_XB 64         // NTOK/128
#define SHARED_HBASE 17408
#define HROWS 25600          // CAP_ROWS + NTOK

typedef unsigned short u16;
typedef __attribute__((ext_vector_type(8))) short bf16x8;   // 8 bf16 in 4 VGPRs
typedef __attribute__((ext_vector_type(4))) float f32x4;

// ---------------- ws layout (bytes) ----------------
static constexpr size_t SZ_XB    = (size_t)NTOK * C_ * 2;
static constexpr size_t SZ_WT    = (size_t)E_ * H_ * C_ * 2;
static constexpr size_t SZ_SWT   = (size_t)H_ * C_ * 2;
static constexpr size_t SZ_H     = (size_t)HROWS * H_ * 2;

static constexpr size_t OFF_XB   = 0;
static constexpr size_t OFF_W1T  = OFF_XB   + SZ_XB;
static constexpr size_t OFF_W3T  = OFF_W1T  + SZ_WT;
static constexpr size_t OFF_W2T  = OFF_W3T  + SZ_WT;
static constexpr size_t OFF_SW1T = OFF_W2T  + SZ_WT;
static constexpr size_t OFF_SW3T = OFF_SW1T + SZ_SWT;
static constexpr size_t OFF_SW2T = OFF_SW3T + SZ_SWT;
static constexpr size_t OFF_H    = OFF_SW2T + SZ_SWT;
static constexpr size_t OFF_RIDX = OFF_H    + SZ_H;                 // int[NTOK*2]
static constexpr size_t OFF_RW   = OFF_RIDX + (size_t)NTOK*2*4;     // float[NTOK*2]
static constexpr size_t OFF_OFFS = OFF_RW   + (size_t)NTOK*2*4;     // int[16]
static constexpr size_t OFF_PTOK = OFF_OFFS + 64;                   // int[CAP_ROWS]
static constexpr size_t OFF_PW   = OFF_PTOK + (size_t)CAP_ROWS*4;   // float[CAP_ROWS]
static constexpr size_t OFF_INV  = OFF_PW   + (size_t)CAP_ROWS*4;   // int[NTOK*2]
static constexpr size_t WS_NEED  = OFF_INV  + (size_t)NTOK*2*4;

// out buffer (bf16, HROWS x C_ = 52.4 MB) aliases W1T+W3T (90.2 MB):
// w1t/w3t are dead once gemm1 completes; transposes rewrite them every call.
static constexpr size_t OFF_OUT  = OFF_W1T;

// ---------------- helpers ----------------
__device__ __forceinline__ u16 f2bf(float f) {
  union { float f; uint32_t u; } v; v.f = f;
  uint32_t r = v.u + 0x7FFFu + ((v.u >> 16) & 1u);   // RNE
  return (u16)(r >> 16);
}
__device__ __forceinline__ float bfu(uint32_t v) {
  union { uint32_t u; float f; } x; x.u = v << 16; return x.f;
}

// async global->LDS, 16B per lane; LDS base wave-uniform, lane offset automatic.
__device__ __forceinline__ void gld16(const void* g, void* l) {
  uint32_t lo = (uint32_t)(uintptr_t)l;
  lo = __builtin_amdgcn_readfirstlane(lo);
  __builtin_amdgcn_global_load_lds(
      (const __attribute__((address_space(1))) void*)g,
      (__attribute__((address_space(3))) void*)(uintptr_t)lo, 16, 0, 0);
}

#define MFMA16(A,B,C) __builtin_amdgcn_mfma_f32_16x16x32_bf16((A),(B),(C),0,0,0)

// ---------------- gating: fp32 scores, top-2, plus x->bf16 ----------------
__global__ __launch_bounds__(256) void gate_kernel(
    const float* __restrict__ x, const float* __restrict__ gw,
    const float* __restrict__ bias, u16* __restrict__ xb,
    int* __restrict__ ridx, float* __restrict__ rw)
{
  const int n = blockIdx.x, t = threadIdx.x;
  const float4 v = *(const float4*)(x + (size_t)n * C_ + t * 4);
  union { u16 u[4]; uint2 d; } pk;
  pk.u[0] = f2bf(v.x); pk.u[1] = f2bf(v.y); pk.u[2] = f2bf(v.z); pk.u[3] = f2bf(v.w);
  *(uint2*)(xb + (size_t)n * C_ + t * 4) = pk.d;

  float p[E_];
#pragma unroll
  for (int e = 0; e < E_; ++e) {
    const float4 g = *(const float4*)(gw + (size_t)e * C_ + t * 4);
    p[e] = v.x * g.x + v.y * g.y + v.z * g.z + v.w * g.w;
  }
#pragma unroll
  for (int e = 0; e < E_; ++e)
    for (int off = 32; off > 0; off >>= 1) p[e] += __shfl_down(p[e], off);

  __shared__ float red[4][E_];
  const int wv = t >> 6;
  if ((t & 63) == 0) {
#pragma unroll
    for (int e = 0; e < E_; ++e) red[wv][e] = p[e];
  }
  __syncthreads();
  if (t == 0) {
    float sc[E_], rt[E_];
#pragma unroll
    for (int e = 0; e < E_; ++e) {
      const float d = red[0][e] + red[1][e] + red[2][e] + red[3][e];
      const float s = 1.f / (1.f + expf(-d));
      sc[e] = s; rt[e] = s + bias[e];
    }
    int i0 = 0; float b0 = rt[0];
#pragma unroll
    for (int e = 1; e < E_; ++e) if (rt[e] > b0) { b0 = rt[e]; i0 = e; }
    int i1 = -1; float b1 = -1e30f;
#pragma unroll
    for (int e = 0; e < E_; ++e) if (e != i0 && rt[e] > b1) { b1 = rt[e]; i1 = e; }
    const float s0 = sc[i0], s1 = sc[i1];
    const float inv = 1.f / (s0 + s1 + 1e-8f);
    ridx[2 * n] = i0; ridx[2 * n + 1] = i1;
    rw[2 * n] = s0 * inv; rw[2 * n + 1] = s1 * inv;
  }
}

// ---------------- weight transpose + fp32->bf16 (wide-write tiles) ----------------
// (C x H) fp32 -> (H x C) bf16. Tile: 64 C x 32 H. Writes = 128B segments.
// grid (H/32, C/64, 18), block 256 flat.
__global__ __launch_bounds__(256) void transpose_cs_kernel(
    const float* __restrict__ w1, const float* __restrict__ w3,
    const float* __restrict__ sw1, const float* __restrict__ sw3,
    u16* __restrict__ w1t, u16* __restrict__ w3t,
    u16* __restrict__ sw1t, u16* __restrict__ sw3t)
{
  const int z = blockIdx.z;
  const float* src; u16* dst;
  if      (z < 8)  { src = w1 + (size_t)z * C_ * H_;       dst = w1t + (size_t)z * H_ * C_; }
  else if (z < 16) { src = w3 + (size_t)(z - 8) * C_ * H_; dst = w3t + (size_t)(z - 8) * H_ * C_; }
  else if (z == 16){ src = sw1; dst = sw1t; }
  else             { src = sw3; dst = sw3t; }
  __shared__ float tile[64][33];
  const int t = threadIdx.x;
  const int s0 = blockIdx.x * 32;   // H
  const int r0 = blockIdx.y * 64;   // C
  const int tx = t & 31, ty = t >> 5;
#pragma unroll
  for (int i = 0; i < 8; ++i)
    tile[ty + 8 * i][tx] = src[(size_t)(r0 + ty + 8 * i) * H_ + s0 + tx];
  __syncthreads();
  const int tx2 = t & 63, ty2 = t >> 6;
#pragma unroll
  for (int i = 0; i < 8; ++i) {
    const int hh = ty2 + 4 * i;
    dst[(size_t)(s0 + hh) * C_ + r0 + tx2] = f2bf(tile[tx2][hh]);
  }
}

// (H x C) fp32 -> (C x H) bf16. Tile: 64 H x 32 C. grid (C/32, H/64, 9).
__global__ __launch_bounds__(256) void transpose_sc_kernel(
    const float* __restrict__ w2, const float* __restrict__ sw2,
    u16* __restrict__ w2t, u16* __restrict__ sw2t)
{
  const int z = blockIdx.z;
  const float* src; u16* dst;
  if (z < 8) { src = w2 + (size_t)z * H_ * C_; dst = w2t + (size_t)z * C_ * H_; }
  else       { src = sw2; dst = sw2t; }
  __shared__ float tile[64][33];
  const int t = threadIdx.x;
  const int s0 = blockIdx.x * 32;   // C
  const int r0 = blockIdx.y * 64;   // H
  const int tx = t & 31, ty = t >> 5;
#pragma unroll
  for (int i = 0; i < 8; ++i)
    tile[ty + 8 * i][tx] = src[(size_t)(r0 + ty + 8 * i) * C_ + s0 + tx];
  __syncthreads();
  const int tx2 = t & 63, ty2 = t >> 6;
#pragma unroll
  for (int i = 0; i < 8; ++i) {
    const int cc = ty2 + 4 * i;
    dst[(size_t)(s0 + cc) * H_ + r0 + tx2] = f2bf(tile[tx2][cc]);
  }
}

// ---------------- deterministic routing scan/scatter (single block) ----------------
__global__ __launch_bounds__(256) void route_scan_kernel(
    const int* __restrict__ ridx, const float* __restrict__ rw,
    int* __restrict__ offsets, int* __restrict__ perm_tok,
    float* __restrict__ perm_w, int* __restrict__ invp)
{
  __shared__ int cnt[256][E_];
  __shared__ int pref[E_][257];
  __shared__ int offs[E_ + 1];
  __shared__ int totals[E_];
  const int t = threadIdx.x;
#pragma unroll
  for (int e = 0; e < E_; ++e) cnt[t][e] = 0;
  for (int j = 0; j < 64; ++j) { const int e = ridx[t * 64 + j]; cnt[t][e]++; }
  __syncthreads();
  if (t < E_) {
    int run = 0;
    for (int i = 0; i < 256; ++i) { pref[t][i] = run; run += cnt[i][t]; }
    totals[t] = run; pref[t][256] = run;
  }
  __syncthreads();
  if (t == 0) {
    int o = 0;
    for (int e = 0; e < E_; ++e) { offs[e] = o; o += (totals[e] + 127) & ~127; }
    offs[E_] = o;
    for (int i = 0; i <= E_; ++i) offsets[i] = offs[i];
  }
  __syncthreads();
#pragma unroll
  for (int e = 0; e < E_; ++e) cnt[t][e] = offs[e] + pref[e][t];
  for (int j = 0; j < 64; ++j) {
    const int a = t * 64 + j;
    const int e = ridx[a];
    const int p = cnt[t][e]++;
    perm_tok[p] = a >> 1;
    perm_w[p] = rw[a];
    invp[a] = p;                    // token/slot -> permuted row
  }
  __syncthreads();
  for (int e = 0; e < E_; ++e) {
    for (int p = offs[e] + totals[e] + t; p < offs[e + 1]; p += 256) {
      perm_tok[p] = 0; perm_w[p] = 0.f;     // pads: valid dummy row, zero weight
    }
  }
}

// =====================================================================
// GEMM1 (unchanged from r8 — at structure ceiling ~920 TF):
// h[row,:] = silu(x@W1) * (x@W3) -> bf16. 128x128 tile, BK=64, 4 waves,
// 16x16x32 MFMA, 2-barrier loop, 48KB LDS, 0-conflict swizzle.
// Grid (22, 200): n-tile fastest.
// =====================================================================
__global__ __launch_bounds__(256, 2) void gemm1_m(
    const u16* __restrict__ xb, const u16* __restrict__ w1t_all,
    const u16* __restrict__ w3t_all, const u16* __restrict__ sw1t,
    const u16* __restrict__ sw3t, u16* __restrict__ hbuf,
    const int* __restrict__ offsets, const int* __restrict__ ptok)
{
  __shared__ u16 lds[3 * 8192];   // A | B1 | B3, each 128x64 bf16 (16KB)
  const int t = threadIdx.x;
  const int n0 = blockIdx.x * 128;
  const int by = blockIdx.y;

  const u16 *b1w, *b3w; int row0; size_t hr0; int gather;
  if (by < ROUTED_XB) {
    row0 = by * 128;
    if (row0 >= offsets[8]) return;
    int e = 0;
#pragma unroll
    for (int i = 0; i < 7; ++i) if (row0 >= offsets[i + 1]) e = i + 1;
    b1w = w1t_all + (size_t)e * (H_ * C_);
    b3w = w3t_all + (size_t)e * (H_ * C_);
    hr0 = (size_t)row0; gather = 1;
  } else {
    row0 = (by - ROUTED_XB) * 128;
    b1w = sw1t; b3w = sw3t; hr0 = (size_t)SHARED_HBASE + row0; gather = 0;
  }

  const int tq = t >> 3;
  const int cb = (((t & 7) ^ (tq & 7)) << 4);
  const char* gA[4]; const char* gB1[4]; const char* gB3[4];
#pragma unroll
  for (int i = 0; i < 4; ++i) {
    const int m = i * 32 + tq;
    const int tok = gather ? ptok[row0 + m] : (row0 + m);
    gA[i] = (const char*)xb + (size_t)tok * (C_ * 2) + cb;
    int nn = n0 + m; if (nn > H_ - 1) nn = H_ - 1;    // N tail clamp
    gB1[i] = (const char*)b1w + (size_t)nn * (C_ * 2) + cb;
    gB3[i] = (const char*)b3w + (size_t)nn * (C_ * 2) + cb;
  }
  char* lwave = (char*)lds + (t >> 6) * 1024;

  f32x4 acc1[4][4], acc3[4][4];
#pragma unroll
  for (int i = 0; i < 4; ++i)
#pragma unroll
    for (int j = 0; j < 4; ++j) { acc1[i][j] = f32x4{0,0,0,0}; acc3[i][j] = f32x4{0,0,0,0}; }

  const int lane = t & 63;
  const int l15 = lane & 15, lhi = lane >> 4, swz = lane & 7;
  const int wm = (t >> 7) & 1, wn = (t >> 6) & 1;
  int arow[4], brow[4];
#pragma unroll
  for (int f = 0; f < 4; ++f) {
    arow[f] = (wm * 64 + f * 16 + l15) * 128;
    brow[f] = (wn * 64 + f * 16 + l15) * 128;
  }
  const char* ldsc = (const char*)lds;

  for (int kt = 0; kt < C_ / 64; ++kt) {
    const int kb = kt * 128;
#pragma unroll
    for (int i = 0; i < 4; ++i) gld16(gA[i]  + kb, lwave + i * 4096);
#pragma unroll
    for (int i = 0; i < 4; ++i) gld16(gB1[i] + kb, lwave + 16384 + i * 4096);
#pragma unroll
    for (int i = 0; i < 4; ++i) gld16(gB3[i] + kb, lwave + 32768 + i * 4096);
    __syncthreads();
#pragma unroll
    for (int kk = 0; kk < 2; ++kk) {
      const int co = ((((kk << 2) | lhi)) ^ swz) << 4;
      bf16x8 a[4], b1[4], b3[4];
#pragma unroll
      for (int f = 0; f < 4; ++f) a[f]  = *(const bf16x8*)(ldsc + arow[f] + co);
#pragma unroll
      for (int f = 0; f < 4; ++f) b1[f] = *(const bf16x8*)(ldsc + 16384 + brow[f] + co);
#pragma unroll
      for (int f = 0; f < 4; ++f) b3[f] = *(const bf16x8*)(ldsc + 32768 + brow[f] + co);
#pragma unroll
      for (int mf = 0; mf < 4; ++mf)
#pragma unroll
        for (int nf = 0; nf < 4; ++nf) {
          acc1[mf][nf] = MFMA16(a[mf], b1[nf], acc1[mf][nf]);
          acc3[mf][nf] = MFMA16(a[mf], b3[nf], acc3[mf][nf]);
        }
    }
    __syncthreads();
  }

  const int rbase = wm * 64 + lhi * 4;
  const int cbase = n0 + wn * 64 + l15;
#pragma unroll
  for (int mf = 0; mf < 4; ++mf)
#pragma unroll
    for (int q = 0; q < 4; ++q) {
      const int r = rbase + mf * 16 + q;
      u16* hrow = hbuf + (hr0 + r) * H_;
#pragma unroll
      for (int nf = 0; nf < 4; ++nf) {
        const int c = cbase + nf * 16;
        if (c < H_) {
          const float v1 = acc1[mf][nf][q], v3 = acc3[mf][nf][q];
          const float sv = v1 / (1.f + __expf(-v1));
          hrow[c] = f2bf(sv * v3);
        }
      }
    }
}

// =====================================================================
// GEMM2 (BK=128): out[row,:] = h[row,:] @ W2t, raw bf16 store.
// 128x128 tile, K = 2752 = 21 full BK=128 tiles + 1 half tail.
// LDS: A[128][256B] 32KB | B[128][256B] 32KB = 64KB (2 blocks/CU).
// Swizzle: LDS[r][c16] = G[r][c16 ^ (r&15)]; read chunk (kk*4+lhi)^l15
// -> 16 lanes hit 16 distinct chunks (2 lanes/bank = free).
// Grid (8, 200): n-tile fast.
// =====================================================================
__global__ __launch_bounds__(256, 2) void gemm2_m(
    const u16* __restrict__ hbuf, const u16* __restrict__ w2t_all,
    const u16* __restrict__ sw2t, u16* __restrict__ outb,
    const int* __restrict__ offsets)
{
  __shared__ u16 lds[2 * 16384];
  const int t = threadIdx.x;
  const int n0 = blockIdx.x * 128;
  const int by = blockIdx.y;

  int row0; size_t hr0; const u16* bW;
  if (by < ROUTED_XB) {
    row0 = by * 128;
    if (row0 >= offsets[8]) return;
    int e = 0;
#pragma unroll
    for (int i = 0; i < 7; ++i) if (row0 >= offsets[i + 1]) e = i + 1;
    bW = w2t_all + (size_t)e * (C_ * H_);
    hr0 = (size_t)row0;
  } else {
    row0 = (by - ROUTED_XB) * 128;
    bW = sw2t; hr0 = (size_t)SHARED_HBASE + row0;
  }

  // staging: 8 issues per matrix; issue i covers rows i*16+tq (tq=t>>4),
  // phys chunk t&15 of the 256B row; source chunk pre-swizzled (t&15)^(tq&15).
  const int tq = t >> 4;
  const int cb = (((t & 15) ^ (tq & 15)) << 4);
  const char* gA[8]; const char* gB[8];
#pragma unroll
  for (int i = 0; i < 8; ++i) {
    const int m = i * 16 + tq;
    gA[i] = (const char*)hbuf + (hr0 + m) * (size_t)(H_ * 2) + cb;
    gB[i] = (const char*)bW + (size_t)(n0 + m) * (H_ * 2) + cb;
  }
  char* lwave = (char*)lds + (t >> 6) * 1024;

  f32x4 acc[4][4];
#pragma unroll
  for (int i = 0; i < 4; ++i)
#pragma unroll
    for (int j = 0; j < 4; ++j) acc[i][j] = f32x4{0,0,0,0};

  const int lane = t & 63;
  const int l15 = lane & 15, lhi = lane >> 4;
  const int wm = (t >> 7) & 1, wn = (t >> 6) & 1;
  int arow[4], brow[4];
#pragma unroll
  for (int f = 0; f < 4; ++f) {
    arow[f] = (wm * 64 + f * 16 + l15) * 256;
    brow[f] = (wn * 64 + f * 16 + l15) * 256;
  }
  const char* ldsc = (const char*)lds;

#define G2_STAGE(kb) do { \
  _Pragma("unroll") for (int i = 0; i < 8; ++i) gld16(gA[i] + (kb), lwave + i * 4096); \
  _Pragma("unroll") for (int i = 0; i < 8; ++i) gld16(gB[i] + (kb), lwave + 32768 + i * 4096); } while (0)
#define G2_KK(kk) do { \
  const int co = ((((kk) << 2) | lhi) ^ l15) << 4; \
  bf16x8 a[4], b[4]; \
  _Pragma("unroll") for (int f = 0; f < 4; ++f) a[f] = *(const bf16x8*)(ldsc + arow[f] + co); \
  _Pragma("unroll") for (int f = 0; f < 4; ++f) b[f] = *(const bf16x8*)(ldsc + 32768 + brow[f] + co); \
  _Pragma("unroll") for (int mf = 0; mf < 4; ++mf) \
    _Pragma("unroll") for (int nf = 0; nf < 4; ++nf) \
      acc[mf][nf] = MFMA16(a[mf], b[nf], acc[mf][nf]); } while (0)

  for (int kt = 0; kt < 21; ++kt) {   // full BK=128 tiles
    G2_STAGE(kt * 256);
    __syncthreads();
#pragma unroll
    for (int kk = 0; kk < 4; ++kk) G2_KK(kk);
    __syncthreads();
  }
  // tail: K-cols 2688..2751 (64 wide). Stage reads up to 128B past the row
  // end (valid ws memory); only kk 0..1 consumed.
  G2_STAGE(21 * 256);
  __syncthreads();
  G2_KK(0); G2_KK(1);

#undef G2_STAGE
#undef G2_KK

  // epilogue: plain bf16 store of raw GEMM output
  const int rbase = wm * 64 + lhi * 4;
  const int cbase = n0 + wn * 64 + l15;
#pragma unroll
  for (int mf = 0; mf < 4; ++mf)
#pragma unroll
    for (int q = 0; q < 4; ++q) {
      u16* orow = outb + (hr0 + rbase + mf * 16 + q) * C_;
#pragma unroll
      for (int nf = 0; nf < 4; ++nf)
        orow[cbase + nf * 16] = f2bf(acc[mf][nf][q]);
    }
}

// ---------------- combine: y[n] = out_sh[n] + g0*out[p0] + g1*out[p1] ----------------
__global__ __launch_bounds__(256) void combine_kernel(
    const u16* __restrict__ outb, const int* __restrict__ invp,
    const float* __restrict__ rw, float* __restrict__ y)
{
  const int n = blockIdx.x, t = threadIdx.x;
  const int c4 = t * 4;
  const int p0 = invp[2 * n], p1 = invp[2 * n + 1];
  const float g0 = rw[2 * n], g1 = rw[2 * n + 1];
  const uint2 s = *(const uint2*)(outb + ((size_t)SHARED_HBASE + n) * C_ + c4);
  const uint2 a = *(const uint2*)(outb + (size_t)p0 * C_ + c4);
  const uint2 b = *(const uint2*)(outb + (size_t)p1 * C_ + c4);
  float4 o;
  o.x = bfu(s.x & 0xffffu) + g0 * bfu(a.x & 0xffffu) + g1 * bfu(b.x & 0xffffu);
  o.y = bfu(s.x >> 16)     + g0 * bfu(a.x >> 16)     + g1 * bfu(b.x >> 16);
  o.z = bfu(s.y & 0xffffu) + g0 * bfu(a.y & 0xffffu) + g1 * bfu(b.y & 0xffffu);
  o.w = bfu(s.y >> 16)     + g0 * bfu(a.y >> 16)     + g1 * bfu(b.y >> 16);
  *(float4*)(y + (size_t)n * C_ + c4) = o;
}

// ---------------- launch ----------------
extern "C" void kernel_launch(void* const* d_in, const int* in_sizes, int n_in,
                              void* d_out, int out_size, void* d_ws, size_t ws_size,
                              hipStream_t stream)
{
  const float* x    = (const float*)d_in[0];
  const float* gw   = (const float*)d_in[1];
  const float* bias = (const float*)d_in[2];
  const float* w1   = (const float*)d_in[3];
  const float* w2   = (const float*)d_in[4];
  const float* w3   = (const float*)d_in[5];
  const float* sw1  = (const float*)d_in[6];
  const float* sw2  = (const float*)d_in[7];
  const float* sw3  = (const float*)d_in[8];
  float* y = (float*)d_out;
  char* ws = (char*)d_ws;
  if (ws_size < WS_NEED) return;   // distinctive failure: output stays poisoned

  u16*   xb    = (u16*)(ws + OFF_XB);
  u16*   w1t   = (u16*)(ws + OFF_W1T);
  u16*   w3t   = (u16*)(ws + OFF_W3T);
  u16*   w2t   = (u16*)(ws + OFF_W2T);
  u16*   sw1t  = (u16*)(ws + OFF_SW1T);
  u16*   sw3t  = (u16*)(ws + OFF_SW3T);
  u16*   sw2t  = (u16*)(ws + OFF_SW2T);
  u16*   hbuf  = (u16*)(ws + OFF_H);
  u16*   outb  = (u16*)(ws + OFF_OUT);   // aliases w1t/w3t (dead after gemm1)
  int*   ridx  = (int*)(ws + OFF_RIDX);
  float* rwt   = (float*)(ws + OFF_RW);
  int*   offs  = (int*)(ws + OFF_OFFS);
  int*   ptok  = (int*)(ws + OFF_PTOK);
  float* pw    = (float*)(ws + OFF_PW);
  int*   invp  = (int*)(ws + OFF_INV);

  gate_kernel<<<NTOK, 256, 0, stream>>>(x, gw, bias, xb, ridx, rwt);
  transpose_cs_kernel<<<dim3(H_ / 32, C_ / 64, 18), 256, 0, stream>>>(
      w1, w3, sw1, sw3, w1t, w3t, sw1t, sw3t);
  transpose_sc_kernel<<<dim3(C_ / 32, H_ / 64, 9), 256, 0, stream>>>(
      w2, sw2, w2t, sw2t);
  route_scan_kernel<<<1, 256, 0, stream>>>(ridx, rwt, offs, ptok, pw, invp);

  // GEMM1: n-tile fastest (co-resident blocks share the A-tile)
  gemm1_m<<<dim3(22, ROUTED_XB + SHARED_XB), 256, 0, stream>>>(
      xb, w1t, w3t, sw1t, sw3t, hbuf, offs, ptok);
  // GEMM2: raw rows -> outb (bf16), no atomics, BK=128
  gemm2_m<<<dim3(8, ROUTED_XB + SHARED_XB), 256, 0, stream>>>(
      hbuf, w2t, sw2t, outb, offs);
  // combine: gather + weight + sum -> y
  combine_kernel<<<NTOK, 256, 0, stream>>>(outb, invp, rwt, y);
}

// Round 10
// 637.834 us; speedup vs baseline: 1.0481x; 1.0481x over previous
//
#include <hip/hip_runtime.h>
#include <hip/hip_bf16.h>
#include <stdint.h>

// ---------------- problem constants ----------------
#define E_ 8
#define C_ 1024
#define H_ 2752
#define NTOK 8192            // B*T = 4*2048
#define CAP_ROWS 17408       // 16384 assignments + 8*128 pad, 128-aligned
#define ROUTED_XB 136        // CAP_ROWS/128
#define SHARED_XB 64         // NTOK/128
#define SHARED_HBASE 17408
#define HROWS 25600          // CAP_ROWS + NTOK

typedef unsigned short u16;
typedef __attribute__((ext_vector_type(8))) short bf16x8;   // 8 bf16 in 4 VGPRs
typedef __attribute__((ext_vector_type(4))) float f32x4;

// ---------------- ws layout (bytes) ----------------
static constexpr size_t SZ_XB    = (size_t)NTOK * C_ * 2;
static constexpr size_t SZ_WT    = (size_t)E_ * H_ * C_ * 2;
static constexpr size_t SZ_SWT   = (size_t)H_ * C_ * 2;
static constexpr size_t SZ_H     = (size_t)HROWS * H_ * 2;

static constexpr size_t OFF_XB   = 0;
static constexpr size_t OFF_W1T  = OFF_XB   + SZ_XB;
static constexpr size_t OFF_W3T  = OFF_W1T  + SZ_WT;
static constexpr size_t OFF_W2T  = OFF_W3T  + SZ_WT;
static constexpr size_t OFF_SW1T = OFF_W2T  + SZ_WT;
static constexpr size_t OFF_SW3T = OFF_SW1T + SZ_SWT;
static constexpr size_t OFF_SW2T = OFF_SW3T + SZ_SWT;
static constexpr size_t OFF_H    = OFF_SW2T + SZ_SWT;
static constexpr size_t OFF_RIDX = OFF_H    + SZ_H;                 // int[NTOK*2]
static constexpr size_t OFF_RW   = OFF_RIDX + (size_t)NTOK*2*4;     // float[NTOK*2]
static constexpr size_t OFF_OFFS = OFF_RW   + (size_t)NTOK*2*4;     // int[16]
static constexpr size_t OFF_PTOK = OFF_OFFS + 64;                   // int[CAP_ROWS]
static constexpr size_t OFF_PW   = OFF_PTOK + (size_t)CAP_ROWS*4;   // float[CAP_ROWS]
static constexpr size_t OFF_INV  = OFF_PW   + (size_t)CAP_ROWS*4;   // int[NTOK*2]
static constexpr size_t WS_NEED  = OFF_INV  + (size_t)NTOK*2*4;

// out buffer (bf16, HROWS x C_ = 52.4 MB) aliases W1T+W3T (90.2 MB):
// w1t/w3t are dead once gemm1 completes; transposes rewrite them every call.
static constexpr size_t OFF_OUT  = OFF_W1T;

// ---------------- helpers ----------------
__device__ __forceinline__ u16 f2bf(float f) {
  union { float f; uint32_t u; } v; v.f = f;
  uint32_t r = v.u + 0x7FFFu + ((v.u >> 16) & 1u);   // RNE
  return (u16)(r >> 16);
}
__device__ __forceinline__ float bfu(uint32_t v) {
  union { uint32_t u; float f; } x; x.u = v << 16; return x.f;
}

// async global->LDS, 16B per lane; LDS base wave-uniform, lane offset automatic.
__device__ __forceinline__ void gld16(const void* g, void* l) {
  uint32_t lo = (uint32_t)(uintptr_t)l;
  lo = __builtin_amdgcn_readfirstlane(lo);
  __builtin_amdgcn_global_load_lds(
      (const __attribute__((address_space(1))) void*)g,
      (__attribute__((address_space(3))) void*)(uintptr_t)lo, 16, 0, 0);
}

#define MFMA16(A,B,C) __builtin_amdgcn_mfma_f32_16x16x32_bf16((A),(B),(C),0,0,0)

// ---------------- gating: fp32 scores, top-2, plus x->bf16 ----------------
__global__ __launch_bounds__(256) void gate_kernel(
    const float* __restrict__ x, const float* __restrict__ gw,
    const float* __restrict__ bias, u16* __restrict__ xb,
    int* __restrict__ ridx, float* __restrict__ rw)
{
  const int n = blockIdx.x, t = threadIdx.x;
  const float4 v = *(const float4*)(x + (size_t)n * C_ + t * 4);
  union { u16 u[4]; uint2 d; } pk;
  pk.u[0] = f2bf(v.x); pk.u[1] = f2bf(v.y); pk.u[2] = f2bf(v.z); pk.u[3] = f2bf(v.w);
  *(uint2*)(xb + (size_t)n * C_ + t * 4) = pk.d;

  float p[E_];
#pragma unroll
  for (int e = 0; e < E_; ++e) {
    const float4 g = *(const float4*)(gw + (size_t)e * C_ + t * 4);
    p[e] = v.x * g.x + v.y * g.y + v.z * g.z + v.w * g.w;
  }
#pragma unroll
  for (int e = 0; e < E_; ++e)
    for (int off = 32; off > 0; off >>= 1) p[e] += __shfl_down(p[e], off);

  __shared__ float red[4][E_];
  const int wv = t >> 6;
  if ((t & 63) == 0) {
#pragma unroll
    for (int e = 0; e < E_; ++e) red[wv][e] = p[e];
  }
  __syncthreads();
  if (t == 0) {
    float sc[E_], rt[E_];
#pragma unroll
    for (int e = 0; e < E_; ++e) {
      const float d = red[0][e] + red[1][e] + red[2][e] + red[3][e];
      const float s = 1.f / (1.f + expf(-d));
      sc[e] = s; rt[e] = s + bias[e];
    }
    int i0 = 0; float b0 = rt[0];
#pragma unroll
    for (int e = 1; e < E_; ++e) if (rt[e] > b0) { b0 = rt[e]; i0 = e; }
    int i1 = -1; float b1 = -1e30f;
#pragma unroll
    for (int e = 0; e < E_; ++e) if (e != i0 && rt[e] > b1) { b1 = rt[e]; i1 = e; }
    const float s0 = sc[i0], s1 = sc[i1];
    const float inv = 1.f / (s0 + s1 + 1e-8f);
    ridx[2 * n] = i0; ridx[2 * n + 1] = i1;
    rw[2 * n] = s0 * inv; rw[2 * n + 1] = s1 * inv;
  }
}

// ---------------- weight transpose + fp32->bf16 (wide-write tiles) ----------------
__global__ __launch_bounds__(256) void transpose_cs_kernel(
    const float* __restrict__ w1, const float* __restrict__ w3,
    const float* __restrict__ sw1, const float* __restrict__ sw3,
    u16* __restrict__ w1t, u16* __restrict__ w3t,
    u16* __restrict__ sw1t, u16* __restrict__ sw3t)
{
  const int z = blockIdx.z;
  const float* src; u16* dst;
  if      (z < 8)  { src = w1 + (size_t)z * C_ * H_;       dst = w1t + (size_t)z * H_ * C_; }
  else if (z < 16) { src = w3 + (size_t)(z - 8) * C_ * H_; dst = w3t + (size_t)(z - 8) * H_ * C_; }
  else if (z == 16){ src = sw1; dst = sw1t; }
  else             { src = sw3; dst = sw3t; }
  __shared__ float tile[64][33];
  const int t = threadIdx.x;
  const int s0 = blockIdx.x * 32;   // H
  const int r0 = blockIdx.y * 64;   // C
  const int tx = t & 31, ty = t >> 5;
#pragma unroll
  for (int i = 0; i < 8; ++i)
    tile[ty + 8 * i][tx] = src[(size_t)(r0 + ty + 8 * i) * H_ + s0 + tx];
  __syncthreads();
  const int tx2 = t & 63, ty2 = t >> 6;
#pragma unroll
  for (int i = 0; i < 8; ++i) {
    const int hh = ty2 + 4 * i;
    dst[(size_t)(s0 + hh) * C_ + r0 + tx2] = f2bf(tile[tx2][hh]);
  }
}

__global__ __launch_bounds__(256) void transpose_sc_kernel(
    const float* __restrict__ w2, const float* __restrict__ sw2,
    u16* __restrict__ w2t, u16* __restrict__ sw2t)
{
  const int z = blockIdx.z;
  const float* src; u16* dst;
  if (z < 8) { src = w2 + (size_t)z * H_ * C_; dst = w2t + (size_t)z * C_ * H_; }
  else       { src = sw2; dst = sw2t; }
  __shared__ float tile[64][33];
  const int t = threadIdx.x;
  const int s0 = blockIdx.x * 32;   // C
  const int r0 = blockIdx.y * 64;   // H
  const int tx = t & 31, ty = t >> 5;
#pragma unroll
  for (int i = 0; i < 8; ++i)
    tile[ty + 8 * i][tx] = src[(size_t)(r0 + ty + 8 * i) * C_ + s0 + tx];
  __syncthreads();
  const int tx2 = t & 63, ty2 = t >> 6;
#pragma unroll
  for (int i = 0; i < 8; ++i) {
    const int cc = ty2 + 4 * i;
    dst[(size_t)(s0 + cc) * H_ + r0 + tx2] = f2bf(tile[tx2][cc]);
  }
}

// ---------------- deterministic routing scan/scatter (single block) ----------------
__global__ __launch_bounds__(256) void route_scan_kernel(
    const int* __restrict__ ridx, const float* __restrict__ rw,
    int* __restrict__ offsets, int* __restrict__ perm_tok,
    float* __restrict__ perm_w, int* __restrict__ invp)
{
  __shared__ int cnt[256][E_];
  __shared__ int pref[E_][257];
  __shared__ int offs[E_ + 1];
  __shared__ int totals[E_];
  const int t = threadIdx.x;
#pragma unroll
  for (int e = 0; e < E_; ++e) cnt[t][e] = 0;
  for (int j = 0; j < 64; ++j) { const int e = ridx[t * 64 + j]; cnt[t][e]++; }
  __syncthreads();
  if (t < E_) {
    int run = 0;
    for (int i = 0; i < 256; ++i) { pref[t][i] = run; run += cnt[i][t]; }
    totals[t] = run; pref[t][256] = run;
  }
  __syncthreads();
  if (t == 0) {
    int o = 0;
    for (int e = 0; e < E_; ++e) { offs[e] = o; o += (totals[e] + 127) & ~127; }
    offs[E_] = o;
    for (int i = 0; i <= E_; ++i) offsets[i] = offs[i];
  }
  __syncthreads();
#pragma unroll
  for (int e = 0; e < E_; ++e) cnt[t][e] = offs[e] + pref[e][t];
  for (int j = 0; j < 64; ++j) {
    const int a = t * 64 + j;
    const int e = ridx[a];
    const int p = cnt[t][e]++;
    perm_tok[p] = a >> 1;
    perm_w[p] = rw[a];
    invp[a] = p;                    // token/slot -> permuted row
  }
  __syncthreads();
  for (int e = 0; e < E_; ++e) {
    for (int p = offs[e] + totals[e] + t; p < offs[e + 1]; p += 256) {
      perm_tok[p] = 0; perm_w[p] = 0.f;     // pads: valid dummy row, zero weight
    }
  }
}

// =====================================================================
// GEMM1 (unchanged — at structure ratio 0.0235 B/FLOP, ~920 TF):
// h[row,:] = silu(x@W1) * (x@W3) -> bf16. 128x128 tile, BK=64, 4 waves,
// 16x16x32 MFMA, 2-barrier loop, 48KB LDS, 0-conflict swizzle.
// Grid (22, 200): n-tile fastest.
// =====================================================================
__global__ __launch_bounds__(256, 2) void gemm1_m(
    const u16* __restrict__ xb, const u16* __restrict__ w1t_all,
    const u16* __restrict__ w3t_all, const u16* __restrict__ sw1t,
    const u16* __restrict__ sw3t, u16* __restrict__ hbuf,
    const int* __restrict__ offsets, const int* __restrict__ ptok)
{
  __shared__ u16 lds[3 * 8192];   // A | B1 | B3, each 128x64 bf16 (16KB)
  const int t = threadIdx.x;
  const int n0 = blockIdx.x * 128;
  const int by = blockIdx.y;

  const u16 *b1w, *b3w; int row0; size_t hr0; int gather;
  if (by < ROUTED_XB) {
    row0 = by * 128;
    if (row0 >= offsets[8]) return;
    int e = 0;
#pragma unroll
    for (int i = 0; i < 7; ++i) if (row0 >= offsets[i + 1]) e = i + 1;
    b1w = w1t_all + (size_t)e * (H_ * C_);
    b3w = w3t_all + (size_t)e * (H_ * C_);
    hr0 = (size_t)row0; gather = 1;
  } else {
    row0 = (by - ROUTED_XB) * 128;
    b1w = sw1t; b3w = sw3t; hr0 = (size_t)SHARED_HBASE + row0; gather = 0;
  }

  const int tq = t >> 3;
  const int cb = (((t & 7) ^ (tq & 7)) << 4);
  const char* gA[4]; const char* gB1[4]; const char* gB3[4];
#pragma unroll
  for (int i = 0; i < 4; ++i) {
    const int m = i * 32 + tq;
    const int tok = gather ? ptok[row0 + m] : (row0 + m);
    gA[i] = (const char*)xb + (size_t)tok * (C_ * 2) + cb;
    int nn = n0 + m; if (nn > H_ - 1) nn = H_ - 1;    // N tail clamp
    gB1[i] = (const char*)b1w + (size_t)nn * (C_ * 2) + cb;
    gB3[i] = (const char*)b3w + (size_t)nn * (C_ * 2) + cb;
  }
  char* lwave = (char*)lds + (t >> 6) * 1024;

  f32x4 acc1[4][4], acc3[4][4];
#pragma unroll
  for (int i = 0; i < 4; ++i)
#pragma unroll
    for (int j = 0; j < 4; ++j) { acc1[i][j] = f32x4{0,0,0,0}; acc3[i][j] = f32x4{0,0,0,0}; }

  const int lane = t & 63;
  const int l15 = lane & 15, lhi = lane >> 4, swz = lane & 7;
  const int wm = (t >> 7) & 1, wn = (t >> 6) & 1;
  int arow[4], brow[4];
#pragma unroll
  for (int f = 0; f < 4; ++f) {
    arow[f] = (wm * 64 + f * 16 + l15) * 128;
    brow[f] = (wn * 64 + f * 16 + l15) * 128;
  }
  const char* ldsc = (const char*)lds;

  for (int kt = 0; kt < C_ / 64; ++kt) {
    const int kb = kt * 128;
#pragma unroll
    for (int i = 0; i < 4; ++i) gld16(gA[i]  + kb, lwave + i * 4096);
#pragma unroll
    for (int i = 0; i < 4; ++i) gld16(gB1[i] + kb, lwave + 16384 + i * 4096);
#pragma unroll
    for (int i = 0; i < 4; ++i) gld16(gB3[i] + kb, lwave + 32768 + i * 4096);
    __syncthreads();
#pragma unroll
    for (int kk = 0; kk < 2; ++kk) {
      const int co = ((((kk << 2) | lhi)) ^ swz) << 4;
      bf16x8 a[4], b1[4], b3[4];
#pragma unroll
      for (int f = 0; f < 4; ++f) a[f]  = *(const bf16x8*)(ldsc + arow[f] + co);
#pragma unroll
      for (int f = 0; f < 4; ++f) b1[f] = *(const bf16x8*)(ldsc + 16384 + brow[f] + co);
#pragma unroll
      for (int f = 0; f < 4; ++f) b3[f] = *(const bf16x8*)(ldsc + 32768 + brow[f] + co);
#pragma unroll
      for (int mf = 0; mf < 4; ++mf)
#pragma unroll
        for (int nf = 0; nf < 4; ++nf) {
          acc1[mf][nf] = MFMA16(a[mf], b1[nf], acc1[mf][nf]);
          acc3[mf][nf] = MFMA16(a[mf], b3[nf], acc3[mf][nf]);
        }
    }
    __syncthreads();
  }

  const int rbase = wm * 64 + lhi * 4;
  const int cbase = n0 + wn * 64 + l15;
#pragma unroll
  for (int mf = 0; mf < 4; ++mf)
#pragma unroll
    for (int q = 0; q < 4; ++q) {
      const int r = rbase + mf * 16 + q;
      u16* hrow = hbuf + (hr0 + r) * H_;
#pragma unroll
      for (int nf = 0; nf < 4; ++nf) {
        const int c = cbase + nf * 16;
        if (c < H_) {
          const float v1 = acc1[mf][nf][q], v3 = acc3[mf][nf][q];
          const float sv = v1 / (1.f + __expf(-v1));
          hrow[c] = f2bf(sv * v3);
        }
      }
    }
}

// =====================================================================
// GEMM2 (wave reshaped 64x128 -> 0.0235 B/FLOP, matches gemm1 ratio):
// out[row,:] = h[row,:] @ W2t, raw bf16 store. Tile 128x256, BK=64,
// 4 waves (2M x 2N), wave = 64 rows x 128 cols (mf=4, nf=8).
// K = 2752 = 43 exact BK=64 tiles. LDS: A 16KB | B 32KB = 48KB.
// Same 0-conflict swizzle as gemm1. Grid (4, 200): n-tile fast.
// =====================================================================
__global__ __launch_bounds__(256, 2) void gemm2_m(
    const u16* __restrict__ hbuf, const u16* __restrict__ w2t_all,
    const u16* __restrict__ sw2t, u16* __restrict__ outb,
    const int* __restrict__ offsets)
{
  __shared__ u16 lds[3 * 8192];   // A 16KB | B 32KB
  const int t = threadIdx.x;
  const int n0 = blockIdx.x * 256;
  const int by = blockIdx.y;

  int row0; size_t hr0; const u16* bW;
  if (by < ROUTED_XB) {
    row0 = by * 128;
    if (row0 >= offsets[8]) return;
    int e = 0;
#pragma unroll
    for (int i = 0; i < 7; ++i) if (row0 >= offsets[i + 1]) e = i + 1;
    bW = w2t_all + (size_t)e * (C_ * H_);
    hr0 = (size_t)row0;
  } else {
    row0 = (by - ROUTED_XB) * 128;
    bW = sw2t; hr0 = (size_t)SHARED_HBASE + row0;
  }

  const int tq = t >> 3;
  const int cb = (((t & 7) ^ (tq & 7)) << 4);
  const char* gA[4]; const char* gB[8];
#pragma unroll
  for (int i = 0; i < 4; ++i)
    gA[i] = (const char*)hbuf + (hr0 + i * 32 + tq) * (size_t)(H_ * 2) + cb;
#pragma unroll
  for (int i = 0; i < 8; ++i)
    gB[i] = (const char*)bW + (size_t)(n0 + i * 32 + tq) * (H_ * 2) + cb;
  char* lwave = (char*)lds + (t >> 6) * 1024;

  f32x4 acc[4][8];
#pragma unroll
  for (int i = 0; i < 4; ++i)
#pragma unroll
    for (int j = 0; j < 8; ++j) acc[i][j] = f32x4{0,0,0,0};

  const int lane = t & 63;
  const int l15 = lane & 15, lhi = lane >> 4, swz = lane & 7;
  const int wv = t >> 6, wm = wv >> 1, wn = wv & 1;
  int arow[4], brow[8];
#pragma unroll
  for (int f = 0; f < 4; ++f) arow[f] = (wm * 64 + f * 16 + l15) * 128;
#pragma unroll
  for (int f = 0; f < 8; ++f) brow[f] = (wn * 128 + f * 16 + l15) * 128;
  const char* ldsc = (const char*)lds;

  for (int kt = 0; kt < 43; ++kt) {   // K = 2752, exact
    const int kb = kt * 128;
#pragma unroll
    for (int i = 0; i < 4; ++i) gld16(gA[i] + kb, lwave + i * 4096);
#pragma unroll
    for (int i = 0; i < 8; ++i) gld16(gB[i] + kb, lwave + 16384 + i * 4096);
    __syncthreads();
#pragma unroll
    for (int kk = 0; kk < 2; ++kk) {
      const int co = ((((kk << 2) | lhi)) ^ swz) << 4;
      bf16x8 a[4], b[8];
#pragma unroll
      for (int f = 0; f < 4; ++f) a[f] = *(const bf16x8*)(ldsc + arow[f] + co);
#pragma unroll
      for (int f = 0; f < 8; ++f) b[f] = *(const bf16x8*)(ldsc + 16384 + brow[f] + co);
#pragma unroll
      for (int mf = 0; mf < 4; ++mf)
#pragma unroll
        for (int nf = 0; nf < 8; ++nf)
          acc[mf][nf] = MFMA16(a[mf], b[nf], acc[mf][nf]);
    }
    __syncthreads();
  }

  // epilogue: plain bf16 store of raw GEMM output
  const int rbase = wm * 64 + lhi * 4;
  const int cbase = n0 + wn * 128 + l15;
#pragma unroll
  for (int mf = 0; mf < 4; ++mf)
#pragma unroll
    for (int q = 0; q < 4; ++q) {
      u16* orow = outb + (hr0 + rbase + mf * 16 + q) * C_;
#pragma unroll
      for (int nf = 0; nf < 8; ++nf)
        orow[cbase + nf * 16] = f2bf(acc[mf][nf][q]);
    }
}

// ---------------- combine: y[n] = out_sh[n] + g0*out[p0] + g1*out[p1] ----------------
__global__ __launch_bounds__(256) void combine_kernel(
    const u16* __restrict__ outb, const int* __restrict__ invp,
    const float* __restrict__ rw, float* __restrict__ y)
{
  const int n = blockIdx.x, t = threadIdx.x;
  const int c4 = t * 4;
  const int p0 = invp[2 * n], p1 = invp[2 * n + 1];
  const float g0 = rw[2 * n], g1 = rw[2 * n + 1];
  const uint2 s = *(const uint2*)(outb + ((size_t)SHARED_HBASE + n) * C_ + c4);
  const uint2 a = *(const uint2*)(outb + (size_t)p0 * C_ + c4);
  const uint2 b = *(const uint2*)(outb + (size_t)p1 * C_ + c4);
  float4 o;
  o.x = bfu(s.x & 0xffffu) + g0 * bfu(a.x & 0xffffu) + g1 * bfu(b.x & 0xffffu);
  o.y = bfu(s.x >> 16)     + g0 * bfu(a.x >> 16)     + g1 * bfu(b.x >> 16);
  o.z = bfu(s.y & 0xffffu) + g0 * bfu(a.y & 0xffffu) + g1 * bfu(b.y & 0xffffu);
  o.w = bfu(s.y >> 16)     + g0 * bfu(a.y >> 16)     + g1 * bfu(b.y >> 16);
  *(float4*)(y + (size_t)n * C_ + c4) = o;
}

// ---------------- launch ----------------
extern "C" void kernel_launch(void* const* d_in, const int* in_sizes, int n_in,
                              void* d_out, int out_size, void* d_ws, size_t ws_size,
                              hipStream_t stream)
{
  const float* x    = (const float*)d_in[0];
  const float* gw   = (const float*)d_in[1];
  const float* bias = (const float*)d_in[2];
  const float* w1   = (const float*)d_in[3];
  const float* w2   = (const float*)d_in[4];
  const float* w3   = (const float*)d_in[5];
  const float* sw1  = (const float*)d_in[6];
  const float* sw2  = (const float*)d_in[7];
  const float* sw3  = (const float*)d_in[8];
  float* y = (float*)d_out;
  char* ws = (char*)d_ws;
  if (ws_size < WS_NEED) return;   // distinctive failure: output stays poisoned

  u16*   xb    = (u16*)(ws + OFF_XB);
  u16*   w1t   = (u16*)(ws + OFF_W1T);
  u16*   w3t   = (u16*)(ws + OFF_W3T);
  u16*   w2t   = (u16*)(ws + OFF_W2T);
  u16*   sw1t  = (u16*)(ws + OFF_SW1T);
  u16*   sw3t  = (u16*)(ws + OFF_SW3T);
  u16*   sw2t  = (u16*)(ws + OFF_SW2T);
  u16*   hbuf  = (u16*)(ws + OFF_H);
  u16*   outb  = (u16*)(ws + OFF_OUT);   // aliases w1t/w3t (dead after gemm1)
  int*   ridx  = (int*)(ws + OFF_RIDX);
  float* rwt   = (float*)(ws + OFF_RW);
  int*   offs  = (int*)(ws + OFF_OFFS);
  int*   ptok  = (int*)(ws + OFF_PTOK);
  float* pw    = (float*)(ws + OFF_PW);
  int*   invp  = (int*)(ws + OFF_INV);

  gate_kernel<<<NTOK, 256, 0, stream>>>(x, gw, bias, xb, ridx, rwt);
  transpose_cs_kernel<<<dim3(H_ / 32, C_ / 64, 18), 256, 0, stream>>>(
      w1, w3, sw1, sw3, w1t, w3t, sw1t, sw3t);
  transpose_sc_kernel<<<dim3(C_ / 32, H_ / 64, 9), 256, 0, stream>>>(
      w2, sw2, w2t, sw2t);
  route_scan_kernel<<<1, 256, 0, stream>>>(ridx, rwt, offs, ptok, pw, invp);

  // GEMM1: n-tile fastest (co-resident blocks share the A-tile)
  gemm1_m<<<dim3(22, ROUTED_XB + SHARED_XB), 256, 0, stream>>>(
      xb, w1t, w3t, sw1t, sw3t, hbuf, offs, ptok);
  // GEMM2: raw rows -> outb (bf16), no atomics, tile 128x256
  gemm2_m<<<dim3(4, ROUTED_XB + SHARED_XB), 256, 0, stream>>>(
      hbuf, w2t, sw2t, outb, offs);
  // combine: gather + weight + sum -> y
  combine_kernel<<<NTOK, 256, 0, stream>>>(outb, invp, rwt, y);
}